// Round 5
// baseline (80.067 us; speedup 1.0000x reference)
//
#include <hip/hip_runtime.h>

// B=2048, N=8192, F=512, H=8, F_=64
// Identity: softmax_n(e1[b]+e2[n]) == softmax_n(e2[n]) => output independent of b.
// Deferred normalization (softmax shift-invariant; e2 ~ N(0,0.45), exp safe):
//   w2[h] = W[h]@a2[h];  g[h] = sum_n exp(G[n].w2[h]) G[n];  s[h] = sum_n exp(...)
//   out[b,:] = relu((g[h]/s[h]) @ W[h])   broadcast over b.
//
// Round-4 analysis: dispatch boundary ~7us each; work ~11us. => minimize dispatches.
// 2 kernels:
//  k_init (64 blk): zero g/s/counter (visible at kernel boundary) + w2 = W@a2
//  k_fused(256 blk, co-resident): G-pass + atomicAdd g/s + counter spin-sync
//                                 + distributed vr slice + output write.

#define HF   8
#define FDIM 512
#define FE   64
#define NG   8192
#define BX   2048
#define K2B  256              // k_fused blocks; <= 256 CUs => co-resident
#define ROWS (NG / K2B)       // 32 rows of G per block

// ws float layout: [0]=counter(uint) | [16..4112)=w2 | [4224..8320)=g | [8384..8392)=s
#define WS_W2 16
#define WS_G  4224
#define WS_S  8384

__global__ __launch_bounds__(256) void k_init(const float* __restrict__ W,
                                              const float* __restrict__ att,
                                              float* __restrict__ ws) {
    int bid = blockIdx.x, tid = threadIdx.x;
    int idx = bid * 256 + tid;                     // 0..16383
    // zero g, s, counter (normal stores; kernel-end flush publishes them)
    if (idx < 4096) ws[WS_G + idx] = 0.f;
    if (idx >= 4096 && idx < 4104) ws[WS_S + (idx - 4096)] = 0.f;
    if (idx == 4104) *reinterpret_cast<unsigned int*>(ws) = 0u;

    // w2: 64 outputs per block, 4 threads per output (16 floats each)
    int o = bid * 64 + (tid >> 2);                 // 0..4095  (o = h*512 + f)
    int sub = tid & 3;
    int h = o >> 9;
    const float* wp = W + (size_t)o * FE + sub * 16;
    const float* a2 = att + h * (2 * FE) + FE + sub * 16;
    float s = 0.f;
#pragma unroll
    for (int e = 0; e < 16; e += 4) {
        float4 w4 = *reinterpret_cast<const float4*>(wp + e);
        s += w4.x * a2[e] + w4.y * a2[e + 1] + w4.z * a2[e + 2] + w4.w * a2[e + 3];
    }
    s += __shfl_xor(s, 1, 64);
    s += __shfl_xor(s, 2, 64);
    if (sub == 0) ws[WS_W2 + o] = s;
}

__global__ __launch_bounds__(256, 1) void k_fused(const float* __restrict__ G,
                                                  const float* __restrict__ W,
                                                  float* __restrict__ ws,
                                                  float* __restrict__ out) {
    __shared__ float lds[HF * FDIM];               // 16 KiB
    __shared__ float s_lds[4 * HF];
    __shared__ float gh[FDIM];
    __shared__ float vp[16][17];
    __shared__ float vrs[16];
    __shared__ float s_h_lds;

    int bid = blockIdx.x, tid = threadIdx.x;
    int wave = tid >> 6, lane = tid & 63;
    const float* w2g = ws + WS_W2;
    float* g = ws + WS_G;
    float* sdenom = ws + WS_S;
    unsigned int* counter = reinterpret_cast<unsigned int*>(ws);

    // ---------------- Phase A: G pass (partial g, s) ----------------
    float4 w2a[HF], w2b[HF];
#pragma unroll
    for (int h = 0; h < HF; ++h) {
        const float* wp = w2g + h * FDIM + lane * 8;
        w2a[h] = *reinterpret_cast<const float4*>(wp);
        w2b[h] = *reinterpret_cast<const float4*>(wp + 4);
    }
    float4 accA[HF], accB[HF];
#pragma unroll
    for (int h = 0; h < HF; ++h) {
        accA[h] = make_float4(0.f, 0.f, 0.f, 0.f);
        accB[h] = make_float4(0.f, 0.f, 0.f, 0.f);
    }
    float s_acc[HF] = {};

    int n0 = bid * ROWS + wave * (ROWS / 4);
    for (int r = 0; r < ROWS / 4; ++r) {
        const float* gp = G + (size_t)(n0 + r) * FDIM + lane * 8;
        float4 g0 = *reinterpret_cast<const float4*>(gp);
        float4 g1 = *reinterpret_cast<const float4*>(gp + 4);
        float e[HF];
#pragma unroll
        for (int h = 0; h < HF; ++h)
            e[h] = g0.x * w2a[h].x + g0.y * w2a[h].y + g0.z * w2a[h].z + g0.w * w2a[h].w
                 + g1.x * w2b[h].x + g1.y * w2b[h].y + g1.z * w2b[h].z + g1.w * w2b[h].w;
#pragma unroll
        for (int off = 32; off > 0; off >>= 1) {
#pragma unroll
            for (int h = 0; h < HF; ++h) e[h] += __shfl_xor(e[h], off, 64);
        }
#pragma unroll
        for (int h = 0; h < HF; ++h) {
            float w = __expf(e[h]);                // identical across lanes
            s_acc[h] += w;
            accA[h].x = fmaf(w, g0.x, accA[h].x);
            accA[h].y = fmaf(w, g0.y, accA[h].y);
            accA[h].z = fmaf(w, g0.z, accA[h].z);
            accA[h].w = fmaf(w, g0.w, accA[h].w);
            accB[h].x = fmaf(w, g1.x, accB[h].x);
            accB[h].y = fmaf(w, g1.y, accB[h].y);
            accB[h].z = fmaf(w, g1.z, accB[h].z);
            accB[h].w = fmaf(w, g1.w, accB[h].w);
        }
    }

    // fixed-order 4-wave combine in LDS (deterministic within block)
    for (int w = 0; w < 4; ++w) {
        if (wave == w) {
#pragma unroll
            for (int h = 0; h < HF; ++h) {
                float* dst = lds + h * FDIM + lane * 8;
                if (w == 0) {
                    *reinterpret_cast<float4*>(dst)     = accA[h];
                    *reinterpret_cast<float4*>(dst + 4) = accB[h];
                } else {
                    float4 t0 = *reinterpret_cast<float4*>(dst);
                    float4 t1 = *reinterpret_cast<float4*>(dst + 4);
                    t0.x += accA[h].x; t0.y += accA[h].y; t0.z += accA[h].z; t0.w += accA[h].w;
                    t1.x += accB[h].x; t1.y += accB[h].y; t1.z += accB[h].z; t1.w += accB[h].w;
                    *reinterpret_cast<float4*>(dst)     = t0;
                    *reinterpret_cast<float4*>(dst + 4) = t1;
                }
            }
            if (lane == 0) {
#pragma unroll
                for (int h = 0; h < HF; ++h) s_lds[w * HF + h] = s_acc[h];
            }
        }
        __syncthreads();
    }

    // global accumulation (device-scope atomics -> coherent point)
    for (int i = tid; i < HF * FDIM; i += 256) atomicAdd(&g[i], lds[i]);
    if (tid < HF)
        atomicAdd(&sdenom[tid],
                  (s_lds[tid] + s_lds[HF + tid]) + (s_lds[2 * HF + tid] + s_lds[3 * HF + tid]));

    // ---------------- spin-sync (single, hand-rolled) ----------------
    __threadfence();
    __syncthreads();
    if (tid == 0) {
        atomicAdd(counter, 1u);
        int iters = 0;
        while (__hip_atomic_load(counter, __ATOMIC_ACQUIRE, __HIP_MEMORY_SCOPE_AGENT) < K2B) {
            __builtin_amdgcn_s_sleep(2);
            if (++iters > 2000000) break;          // escape hatch: fail gracefully, never hang
        }
    }
    __syncthreads();
    __threadfence();

    // ---------------- Phase B: vr slice + output write ----------------
    // 32 column-slices (h, 16 e's) x 8 row-chunks of 256 rows
    int slice = bid & 31, rowchunk = bid >> 5;
    int h = slice >> 2, e0 = (slice & 3) * 16;

    // stage g[h,:] and s[h] via agent-scope atomic loads (bypass possibly-stale L2)
    for (int i = tid; i < FDIM; i += 256)
        gh[i] = __hip_atomic_load(&g[h * FDIM + i], __ATOMIC_RELAXED, __HIP_MEMORY_SCOPE_AGENT);
    if (tid == 0)
        s_h_lds = __hip_atomic_load(&sdenom[h], __ATOMIC_RELAXED, __HIP_MEMORY_SCOPE_AGENT);
    __syncthreads();

    // vr[j] = sum_f gh[f] * W[h, f, e0+j]
    int j = tid & 15, fg = tid >> 4;               // fg: 16 groups of 32 f's
    {
        const float* wp = W + ((size_t)(h * FDIM + fg * 32)) * FE + e0 + j;
        float acc = 0.f;
#pragma unroll 8
        for (int k = 0; k < 32; ++k)
            acc = fmaf(gh[fg * 32 + k], wp[(size_t)k * FE], acc);
        vp[fg][j] = acc;
    }
    __syncthreads();
    if (tid < 16) {
        float v = 0.f;
#pragma unroll
        for (int k = 0; k < 16; ++k) v += vp[k][tid];
        vrs[tid] = fmaxf(v / s_h_lds, 0.f);
    }
    __syncthreads();

    // write 256 unique rows x 64 B column chunk
    int r = rowchunk * 256 + tid;
    float4* dst = reinterpret_cast<float4*>(out + (size_t)r * FDIM + h * FE + e0);
    float4 o0 = make_float4(vrs[0],  vrs[1],  vrs[2],  vrs[3]);
    float4 o1 = make_float4(vrs[4],  vrs[5],  vrs[6],  vrs[7]);
    float4 o2 = make_float4(vrs[8],  vrs[9],  vrs[10], vrs[11]);
    float4 o3 = make_float4(vrs[12], vrs[13], vrs[14], vrs[15]);
    dst[0] = o0; dst[1] = o1; dst[2] = o2; dst[3] = o3;
}

extern "C" void kernel_launch(void* const* d_in, const int* in_sizes, int n_in,
                              void* d_out, int out_size, void* d_ws, size_t ws_size,
                              hipStream_t stream) {
    // inputs: 0=X (mathematically unused), 1=G, 2=W, 3=att
    const float* G   = (const float*)d_in[1];
    const float* W   = (const float*)d_in[2];
    const float* att = (const float*)d_in[3];
    float* out = (float*)d_out;
    float* ws  = (float*)d_ws;

    k_init <<<64,  256, 0, stream>>>(W, att, ws);
    k_fused<<<K2B, 256, 0, stream>>>(G, W, ws, out);
}

// Round 6
// 42.561 us; speedup vs baseline: 1.8812x; 1.8812x over previous
//
#include <hip/hip_runtime.h>

// B=2048, N=8192, F=512, H=8, F_=64
// Identity: softmax_n(e1[b]+e2[n]) == softmax_n(e2[n]) => output independent of b.
// Deferred normalization (softmax shift-invariant; e2 ~ N(0,0.45), exp safe):
//   w2[h] = W[h]@a2[h];  g[h] = sum_n exp(G[n].w2[h]) G[n];  s[h] = sum_n exp(...)
//   out[b,:] = relu((g[h]/s[h]) @ W[h])   broadcast over b.
//
// Round-5 lesson: __threadfence (L2 writeback-inv on multi-XCD) and ACQUIRE
// polling (invalidate per iteration) cost ~60us. This version is FENCE-FREE:
// all cross-block data moves through coherent-point atomics only:
//   publish: atomicAdd (relaxed, agent scope, bypasses XCD L2)
//   arrive:  relaxed atomic counter add after __syncthreads (which drains vmcnt)
//   spin:    RELAXED atomic polls (no cache invalidates)
//   consume: relaxed agent-scope atomic loads (uncached, read coherent point)

#define HF   8
#define FDIM 512
#define FE   64
#define NG   8192
#define BX   2048
#define K2B  256              // k_fused blocks; <= 256 CUs => co-resident
#define ROWS (NG / K2B)       // 32 rows of G per block

// ws float layout: [0]=counter(uint) | [16..4112)=w2 | [4224..8320)=g | [8384..8392)=s
#define WS_W2 16
#define WS_G  4224
#define WS_S  8384

__global__ __launch_bounds__(256) void k_init(const float* __restrict__ W,
                                              const float* __restrict__ att,
                                              float* __restrict__ ws) {
    int bid = blockIdx.x, tid = threadIdx.x;
    int idx = bid * 256 + tid;                     // 0..16383
    // zero g, s, counter (normal stores; kernel-end flush publishes to coherent point)
    if (idx < 4096) ws[WS_G + idx] = 0.f;
    if (idx >= 4096 && idx < 4104) ws[WS_S + (idx - 4096)] = 0.f;
    if (idx == 4104) *reinterpret_cast<unsigned int*>(ws) = 0u;

    // w2: 64 outputs per block, 4 threads per output (16 floats each)
    int o = bid * 64 + (tid >> 2);                 // 0..4095  (o = h*512 + f)
    int sub = tid & 3;
    int h = o >> 9;
    const float* wp = W + (size_t)o * FE + sub * 16;
    const float* a2 = att + h * (2 * FE) + FE + sub * 16;
    float s = 0.f;
#pragma unroll
    for (int e = 0; e < 16; e += 4) {
        float4 w4 = *reinterpret_cast<const float4*>(wp + e);
        s += w4.x * a2[e] + w4.y * a2[e + 1] + w4.z * a2[e + 2] + w4.w * a2[e + 3];
    }
    s += __shfl_xor(s, 1, 64);
    s += __shfl_xor(s, 2, 64);
    if (sub == 0) ws[WS_W2 + o] = s;
}

__global__ __launch_bounds__(256, 1) void k_fused(const float* __restrict__ G,
                                                  const float* __restrict__ W,
                                                  float* __restrict__ ws,
                                                  float* __restrict__ out) {
    __shared__ float lds[HF * FDIM];               // 16 KiB
    __shared__ float s_lds[4 * HF];
    __shared__ float gh[FDIM];
    __shared__ float vp[16][17];
    __shared__ float vrs[16];
    __shared__ float s_h_lds;

    int bid = blockIdx.x, tid = threadIdx.x;
    int wave = tid >> 6, lane = tid & 63;
    const float* w2g = ws + WS_W2;
    float* g = ws + WS_G;
    float* sdenom = ws + WS_S;
    unsigned int* counter = reinterpret_cast<unsigned int*>(ws);

    // ---------------- Phase A: G pass (partial g, s) ----------------
    float4 w2a[HF], w2b[HF];
#pragma unroll
    for (int h = 0; h < HF; ++h) {
        const float* wp = w2g + h * FDIM + lane * 8;
        w2a[h] = *reinterpret_cast<const float4*>(wp);
        w2b[h] = *reinterpret_cast<const float4*>(wp + 4);
    }
    float4 accA[HF], accB[HF];
#pragma unroll
    for (int h = 0; h < HF; ++h) {
        accA[h] = make_float4(0.f, 0.f, 0.f, 0.f);
        accB[h] = make_float4(0.f, 0.f, 0.f, 0.f);
    }
    float s_acc[HF] = {};

    int n0 = bid * ROWS + wave * (ROWS / 4);
    for (int r = 0; r < ROWS / 4; ++r) {
        const float* gp = G + (size_t)(n0 + r) * FDIM + lane * 8;
        float4 g0 = *reinterpret_cast<const float4*>(gp);
        float4 g1 = *reinterpret_cast<const float4*>(gp + 4);
        float e[HF];
#pragma unroll
        for (int h = 0; h < HF; ++h)
            e[h] = g0.x * w2a[h].x + g0.y * w2a[h].y + g0.z * w2a[h].z + g0.w * w2a[h].w
                 + g1.x * w2b[h].x + g1.y * w2b[h].y + g1.z * w2b[h].z + g1.w * w2b[h].w;
#pragma unroll
        for (int off = 32; off > 0; off >>= 1) {
#pragma unroll
            for (int h = 0; h < HF; ++h) e[h] += __shfl_xor(e[h], off, 64);
        }
#pragma unroll
        for (int h = 0; h < HF; ++h) {
            float w = __expf(e[h]);                // identical across lanes
            s_acc[h] += w;
            accA[h].x = fmaf(w, g0.x, accA[h].x);
            accA[h].y = fmaf(w, g0.y, accA[h].y);
            accA[h].z = fmaf(w, g0.z, accA[h].z);
            accA[h].w = fmaf(w, g0.w, accA[h].w);
            accB[h].x = fmaf(w, g1.x, accB[h].x);
            accB[h].y = fmaf(w, g1.y, accB[h].y);
            accB[h].z = fmaf(w, g1.z, accB[h].z);
            accB[h].w = fmaf(w, g1.w, accB[h].w);
        }
    }

    // fixed-order 4-wave combine in LDS (deterministic within block)
    for (int w = 0; w < 4; ++w) {
        if (wave == w) {
#pragma unroll
            for (int h = 0; h < HF; ++h) {
                float* dst = lds + h * FDIM + lane * 8;
                if (w == 0) {
                    *reinterpret_cast<float4*>(dst)     = accA[h];
                    *reinterpret_cast<float4*>(dst + 4) = accB[h];
                } else {
                    float4 t0 = *reinterpret_cast<float4*>(dst);
                    float4 t1 = *reinterpret_cast<float4*>(dst + 4);
                    t0.x += accA[h].x; t0.y += accA[h].y; t0.z += accA[h].z; t0.w += accA[h].w;
                    t1.x += accB[h].x; t1.y += accB[h].y; t1.z += accB[h].z; t1.w += accB[h].w;
                    *reinterpret_cast<float4*>(dst)     = t0;
                    *reinterpret_cast<float4*>(dst + 4) = t1;
                }
            }
            if (lane == 0) {
#pragma unroll
                for (int h = 0; h < HF; ++h) s_lds[w * HF + h] = s_acc[h];
            }
        }
        __syncthreads();
    }

    // publish partials straight to the coherent point (agent-scope atomics,
    // bypass the non-coherent XCD L2; fire-and-forget, no fence needed)
    for (int i = tid; i < HF * FDIM; i += 256) atomicAdd(&g[i], lds[i]);
    if (tid < HF)
        atomicAdd(&sdenom[tid],
                  (s_lds[tid] + s_lds[HF + tid]) + (s_lds[2 * HF + tid] + s_lds[3 * HF + tid]));

    // ---------------- fence-free spin-sync ----------------
    // __syncthreads drains each wave's vmcnt(0) before the barrier, so all of
    // this block's atomics are complete at the coherent point before arrive.
    __syncthreads();
    if (tid == 0) {
        __hip_atomic_fetch_add(counter, 1u, __ATOMIC_RELAXED, __HIP_MEMORY_SCOPE_AGENT);
        int iters = 0;
        while (__hip_atomic_load(counter, __ATOMIC_RELAXED, __HIP_MEMORY_SCOPE_AGENT) < K2B) {
            __builtin_amdgcn_s_sleep(4);
            if (++iters > 200000) break;           // ~20ms escape hatch: fail, never hang
        }
    }
    __syncthreads();

    // ---------------- Phase B: vr slice + output write ----------------
    // 32 column-slices (h, 16 e's) x 8 row-chunks of 256 rows
    int slice = bid & 31, rowchunk = bid >> 5;
    int h = slice >> 2, e0 = (slice & 3) * 16;

    // read final g/s as relaxed agent-scope atomic loads (uncached -> coherent point)
    for (int i = tid; i < FDIM; i += 256)
        gh[i] = __hip_atomic_load(&g[h * FDIM + i], __ATOMIC_RELAXED, __HIP_MEMORY_SCOPE_AGENT);
    if (tid == 0)
        s_h_lds = __hip_atomic_load(&sdenom[h], __ATOMIC_RELAXED, __HIP_MEMORY_SCOPE_AGENT);
    __syncthreads();

    // vr[j] = sum_f gh[f] * W[h, f, e0+j]
    int j = tid & 15, fg = tid >> 4;               // fg: 16 groups of 32 f's
    {
        const float* wp = W + ((size_t)(h * FDIM + fg * 32)) * FE + e0 + j;
        float acc = 0.f;
#pragma unroll 8
        for (int k = 0; k < 32; ++k)
            acc = fmaf(gh[fg * 32 + k], wp[(size_t)k * FE], acc);
        vp[fg][j] = acc;
    }
    __syncthreads();
    if (tid < 16) {
        float v = 0.f;
#pragma unroll
        for (int k = 0; k < 16; ++k) v += vp[k][tid];
        vrs[tid] = fmaxf(v / s_h_lds, 0.f);
    }
    __syncthreads();

    // write 256 unique rows x 64 B column chunk
    int r = rowchunk * 256 + tid;
    float4* dst = reinterpret_cast<float4*>(out + (size_t)r * FDIM + h * FE + e0);
    float4 o0 = make_float4(vrs[0],  vrs[1],  vrs[2],  vrs[3]);
    float4 o1 = make_float4(vrs[4],  vrs[5],  vrs[6],  vrs[7]);
    float4 o2 = make_float4(vrs[8],  vrs[9],  vrs[10], vrs[11]);
    float4 o3 = make_float4(vrs[12], vrs[13], vrs[14], vrs[15]);
    dst[0] = o0; dst[1] = o1; dst[2] = o2; dst[3] = o3;
}

extern "C" void kernel_launch(void* const* d_in, const int* in_sizes, int n_in,
                              void* d_out, int out_size, void* d_ws, size_t ws_size,
                              hipStream_t stream) {
    // inputs: 0=X (mathematically unused), 1=G, 2=W, 3=att
    const float* G   = (const float*)d_in[1];
    const float* W   = (const float*)d_in[2];
    const float* att = (const float*)d_in[3];
    float* out = (float*)d_out;
    float* ws  = (float*)d_ws;

    k_init <<<64,  256, 0, stream>>>(W, att, ws);
    k_fused<<<K2B, 256, 0, stream>>>(G, W, ws, out);
}

// Round 7
// 41.803 us; speedup vs baseline: 1.9154x; 1.0181x over previous
//
#include <hip/hip_runtime.h>

// B=2048, N=8192, F=512, H=8, F_=64
// Identity: softmax_n(e1[b]+e2[n]) == softmax_n(e2[n]) => output independent of b.
// Deferred normalization (softmax shift-invariant; e2 ~ N(0,0.45), exp safe):
//   w2[h] = W[h]@a2[h];  g[h] = sum_n exp(G[n].w2[h]) G[n];  s[h] = sum_n exp(...)
//   out[b,:] = relu((g[h]/s[h]) @ W[h])   broadcast over b.
//
// Round-6 lesson: aligned atomic publish order = 16 serialized contention
// storms (256-deep RMW chain per address) ~= 40us. Fix: per-block ROTATED
// publish order (chunk (k+bid)&15 at step k) -> bounded by atomic throughput
// (~3.5us), and s published into 64 slots (depth 32) instead of 8 (depth 256).
// Sync stays fence-free: relaxed coherent-point atomics only (round-5 lesson:
// __threadfence / ACQUIRE polls cost ~60us in L2 writebacks/invalidates).

#define HF   8
#define FDIM 512
#define FE   64
#define NG   8192
#define BX   2048
#define K2B  256              // k_fused blocks; <= 256 CUs => co-resident
#define ROWS (NG / K2B)       // 32 rows of G per block

// ws float layout: [0]=counter(uint) | [16..4112)=w2 | [4224..8320)=g | [8384..8448)=s slots
#define WS_W2 16
#define WS_G  4224
#define WS_S  8384

__global__ __launch_bounds__(256) void k_init(const float* __restrict__ W,
                                              const float* __restrict__ att,
                                              float* __restrict__ ws) {
    int bid = blockIdx.x, tid = threadIdx.x;
    int idx = bid * 256 + tid;                     // 0..16383
    // zero g, s slots, counter (normal stores; kernel-end flush publishes)
    if (idx < 4096) ws[WS_G + idx] = 0.f;
    if (idx >= 4096 && idx < 4160) ws[WS_S + (idx - 4096)] = 0.f;
    if (idx == 4160) *reinterpret_cast<unsigned int*>(ws) = 0u;

    // w2: 64 outputs per block, 4 threads per output (16 floats each)
    int o = bid * 64 + (tid >> 2);                 // 0..4095  (o = h*512 + f)
    int sub = tid & 3;
    int h = o >> 9;
    const float* wp = W + (size_t)o * FE + sub * 16;
    const float* a2 = att + h * (2 * FE) + FE + sub * 16;
    float s = 0.f;
#pragma unroll
    for (int e = 0; e < 16; e += 4) {
        float4 w4 = *reinterpret_cast<const float4*>(wp + e);
        s += w4.x * a2[e] + w4.y * a2[e + 1] + w4.z * a2[e + 2] + w4.w * a2[e + 3];
    }
    s += __shfl_xor(s, 1, 64);
    s += __shfl_xor(s, 2, 64);
    if (sub == 0) ws[WS_W2 + o] = s;
}

__global__ __launch_bounds__(256, 1) void k_fused(const float* __restrict__ G,
                                                  const float* __restrict__ W,
                                                  float* __restrict__ ws,
                                                  float* __restrict__ out) {
    __shared__ float lds[HF * FDIM];               // 16 KiB
    __shared__ float s_lds[4 * HF];
    __shared__ float gh[FDIM];
    __shared__ float vp[16][17];
    __shared__ float vrs[16];
    __shared__ float s_h_lds;

    int bid = blockIdx.x, tid = threadIdx.x;
    int wave = tid >> 6, lane = tid & 63;
    const float* w2g = ws + WS_W2;
    float* g = ws + WS_G;
    float* s_slot = ws + WS_S;                     // [h][0..7]
    unsigned int* counter = reinterpret_cast<unsigned int*>(ws);

    // ---------------- Phase A: G pass (partial g, s) ----------------
    float4 w2a[HF], w2b[HF];
#pragma unroll
    for (int h = 0; h < HF; ++h) {
        const float* wp = w2g + h * FDIM + lane * 8;
        w2a[h] = *reinterpret_cast<const float4*>(wp);
        w2b[h] = *reinterpret_cast<const float4*>(wp + 4);
    }
    float4 accA[HF], accB[HF];
#pragma unroll
    for (int h = 0; h < HF; ++h) {
        accA[h] = make_float4(0.f, 0.f, 0.f, 0.f);
        accB[h] = make_float4(0.f, 0.f, 0.f, 0.f);
    }
    float s_acc[HF] = {};

    int n0 = bid * ROWS + wave * (ROWS / 4);
    for (int r = 0; r < ROWS / 4; ++r) {
        const float* gp = G + (size_t)(n0 + r) * FDIM + lane * 8;
        float4 g0 = *reinterpret_cast<const float4*>(gp);
        float4 g1 = *reinterpret_cast<const float4*>(gp + 4);
        float e[HF];
#pragma unroll
        for (int h = 0; h < HF; ++h)
            e[h] = g0.x * w2a[h].x + g0.y * w2a[h].y + g0.z * w2a[h].z + g0.w * w2a[h].w
                 + g1.x * w2b[h].x + g1.y * w2b[h].y + g1.z * w2b[h].z + g1.w * w2b[h].w;
#pragma unroll
        for (int off = 32; off > 0; off >>= 1) {
#pragma unroll
            for (int h = 0; h < HF; ++h) e[h] += __shfl_xor(e[h], off, 64);
        }
#pragma unroll
        for (int h = 0; h < HF; ++h) {
            float w = __expf(e[h]);                // identical across lanes
            s_acc[h] += w;
            accA[h].x = fmaf(w, g0.x, accA[h].x);
            accA[h].y = fmaf(w, g0.y, accA[h].y);
            accA[h].z = fmaf(w, g0.z, accA[h].z);
            accA[h].w = fmaf(w, g0.w, accA[h].w);
            accB[h].x = fmaf(w, g1.x, accB[h].x);
            accB[h].y = fmaf(w, g1.y, accB[h].y);
            accB[h].z = fmaf(w, g1.z, accB[h].z);
            accB[h].w = fmaf(w, g1.w, accB[h].w);
        }
    }

    // fixed-order 4-wave combine in LDS (deterministic within block)
    for (int w = 0; w < 4; ++w) {
        if (wave == w) {
#pragma unroll
            for (int h = 0; h < HF; ++h) {
                float* dst = lds + h * FDIM + lane * 8;
                if (w == 0) {
                    *reinterpret_cast<float4*>(dst)     = accA[h];
                    *reinterpret_cast<float4*>(dst + 4) = accB[h];
                } else {
                    float4 t0 = *reinterpret_cast<float4*>(dst);
                    float4 t1 = *reinterpret_cast<float4*>(dst + 4);
                    t0.x += accA[h].x; t0.y += accA[h].y; t0.z += accA[h].z; t0.w += accA[h].w;
                    t1.x += accB[h].x; t1.y += accB[h].y; t1.z += accB[h].z; t1.w += accB[h].w;
                    *reinterpret_cast<float4*>(dst)     = t0;
                    *reinterpret_cast<float4*>(dst + 4) = t1;
                }
            }
            if (lane == 0) {
#pragma unroll
                for (int h = 0; h < HF; ++h) s_lds[w * HF + h] = s_acc[h];
            }
        }
        __syncthreads();
    }

    // publish partials to the coherent point with PER-BLOCK ROTATED chunk order:
    // block b writes chunk (k+b)&15 at step k -> no chip-wide same-address storms.
#pragma unroll
    for (int k = 0; k < 16; ++k) {
        int i = (((k + bid) & 15) << 8) | tid;
        atomicAdd(&g[i], lds[i]);
    }
    if (tid < HF)
        atomicAdd(&s_slot[tid * 8 + (bid & 7)],
                  (s_lds[tid] + s_lds[HF + tid]) + (s_lds[2 * HF + tid] + s_lds[3 * HF + tid]));

    // ---------------- fence-free spin-sync ----------------
    // __syncthreads drains vmcnt(0), so this block's atomics are complete at
    // the coherent point before the arrive.
    __syncthreads();
    if (tid == 0) {
        __hip_atomic_fetch_add(counter, 1u, __ATOMIC_RELAXED, __HIP_MEMORY_SCOPE_AGENT);
        int iters = 0;
        while (__hip_atomic_load(counter, __ATOMIC_RELAXED, __HIP_MEMORY_SCOPE_AGENT) < K2B) {
            __builtin_amdgcn_s_sleep(2);
            if (++iters > 400000) break;           // escape hatch: fail, never hang
        }
    }
    __syncthreads();

    // ---------------- Phase B: vr slice + output write ----------------
    // 32 column-slices (h, 16 e's) x 8 row-chunks of 256 rows
    int slice = bid & 31, rowchunk = bid >> 5;
    int h = slice >> 2, e0 = (slice & 3) * 16;

    // read final g/s as relaxed agent-scope atomic loads (uncached, coherent point)
    for (int i = tid; i < FDIM; i += 256)
        gh[i] = __hip_atomic_load(&g[h * FDIM + i], __ATOMIC_RELAXED, __HIP_MEMORY_SCOPE_AGENT);
    if (tid == 0) {
        float sv = 0.f;
#pragma unroll
        for (int k = 0; k < 8; ++k)
            sv += __hip_atomic_load(&s_slot[h * 8 + k], __ATOMIC_RELAXED, __HIP_MEMORY_SCOPE_AGENT);
        s_h_lds = sv;
    }
    __syncthreads();

    // vr[j] = sum_f gh[f] * W[h, f, e0+j]
    int j = tid & 15, fg = tid >> 4;               // fg: 16 groups of 32 f's
    {
        const float* wp = W + ((size_t)(h * FDIM + fg * 32)) * FE + e0 + j;
        float acc = 0.f;
#pragma unroll 8
        for (int k = 0; k < 32; ++k)
            acc = fmaf(gh[fg * 32 + k], wp[(size_t)k * FE], acc);
        vp[fg][j] = acc;
    }
    __syncthreads();
    if (tid < 16) {
        float v = 0.f;
#pragma unroll
        for (int k = 0; k < 16; ++k) v += vp[k][tid];
        vrs[tid] = fmaxf(v / s_h_lds, 0.f);
    }
    __syncthreads();

    // write 256 unique rows x 64 B column chunk
    int r = rowchunk * 256 + tid;
    float4* dst = reinterpret_cast<float4*>(out + (size_t)r * FDIM + h * FE + e0);
    float4 o0 = make_float4(vrs[0],  vrs[1],  vrs[2],  vrs[3]);
    float4 o1 = make_float4(vrs[4],  vrs[5],  vrs[6],  vrs[7]);
    float4 o2 = make_float4(vrs[8],  vrs[9],  vrs[10], vrs[11]);
    float4 o3 = make_float4(vrs[12], vrs[13], vrs[14], vrs[15]);
    dst[0] = o0; dst[1] = o1; dst[2] = o2; dst[3] = o3;
}

extern "C" void kernel_launch(void* const* d_in, const int* in_sizes, int n_in,
                              void* d_out, int out_size, void* d_ws, size_t ws_size,
                              hipStream_t stream) {
    // inputs: 0=X (mathematically unused), 1=G, 2=W, 3=att
    const float* G   = (const float*)d_in[1];
    const float* W   = (const float*)d_in[2];
    const float* att = (const float*)d_in[3];
    float* out = (float*)d_out;
    float* ws  = (float*)d_ws;

    k_init <<<64,  256, 0, stream>>>(W, att, ws);
    k_fused<<<K2B, 256, 0, stream>>>(G, W, ws, out);
}